// Round 2
// baseline (465.022 us; speedup 1.0000x reference)
//
#include <hip/hip_runtime.h>
#include <hip/hip_bf16.h>

typedef __attribute__((ext_vector_type(8))) short s8x;   // 8 bf16 = 4 VGPRs (MFMA A/B frag)
typedef __attribute__((ext_vector_type(4))) float f4x;   // MFMA C/D frag
typedef unsigned short u16;
typedef unsigned int u32;

#define NHEADS 16
#define T_ 1024
#define TC_ 2048
#define SCALE_ 0.125f   // 64^-0.5

__device__ __forceinline__ float bf2f(u16 u) { return __uint_as_float(((u32)u) << 16); }
__device__ __forceinline__ u16 f2bf(float f) {
    u32 u = __float_as_uint(f);
    return (u16)((u + 0x7fffu + ((u >> 16) & 1u)) >> 16);  // RNE
}

// async global->LDS, 16B per lane; LDS dst is wave-uniform base + lane*16
__device__ __forceinline__ void gload16(const void* g, void* l) {
    __builtin_amdgcn_global_load_lds((const __attribute__((address_space(1))) u32*)g,
                                     (__attribute__((address_space(3))) u32*)l, 16, 0, 0);
}

// ---- gamma = mean(|W|), W fp32: block partial sums -> atomicAdd ------------
__global__ __launch_bounds__(256) void absmean_k(const float* __restrict__ W,
                                                 float* __restrict__ gsum, int idx) {
    const int n4 = (1024 * 1024) / 4;
    float s = 0.f;
    int stride = gridDim.x * blockDim.x;
    for (int i = blockIdx.x * blockDim.x + threadIdx.x; i < n4; i += stride) {
        float4 v = ((const float4*)W)[i];
        s += fabsf(v.x) + fabsf(v.y) + fabsf(v.z) + fabsf(v.w);
    }
#pragma unroll
    for (int off = 32; off; off >>= 1) s += __shfl_down(s, off, 64);
    __shared__ float ps[4];
    if ((threadIdx.x & 63) == 0) ps[threadIdx.x >> 6] = s;
    __syncthreads();
    if (threadIdx.x == 0) atomicAdd(gsum + idx, ps[0] + ps[1] + ps[2] + ps[3]);
}

// ---- ternary quantize (fp32 W): clip(rint(W/(gamma+eps)),-1,1) exact bf16 --
__global__ __launch_bounds__(256) void quant_k(const float* __restrict__ W, u16* __restrict__ Tq,
                                               const float* __restrict__ gsum, int idx) {
    float gamma = gsum[idx] * (1.0f / 1048576.0f);
    float inv = 1.0f / (gamma + 1e-5f);
    int i = blockIdx.x * 256 + threadIdx.x;   // 4 elems each, grid 1024
    float4 w = ((const float4*)W)[i];
    ushort4 o;
    o.x = f2bf(fminf(1.f, fmaxf(-1.f, rintf(w.x * inv))));
    o.y = f2bf(fminf(1.f, fmaxf(-1.f, rintf(w.y * inv))));
    o.z = f2bf(fminf(1.f, fmaxf(-1.f, rintf(w.z * inv))));
    o.w = f2bf(fminf(1.f, fmaxf(-1.f, rintf(w.w * inv))));
    ((ushort4*)Tq)[i] = o;
}

// ---- fp32 -> bf16 cast (context) ------------------------------------------
__global__ __launch_bounds__(256) void cast_k(const float* __restrict__ src, u16* __restrict__ dst) {
    int i = blockIdx.x * 256 + threadIdx.x;
    float4 v = ((const float4*)src)[i];
    ushort4 o = {f2bf(v.x), f2bf(v.y), f2bf(v.z), f2bf(v.w)};
    ((ushort4*)dst)[i] = o;
}

// ---- LayerNorm(x fp32) -> bf16, one block per row of 1024 -----------------
__global__ __launch_bounds__(256) void ln_k(const float* __restrict__ x, const float* __restrict__ g,
                                            const float* __restrict__ b, u16* __restrict__ xn) {
    int row = blockIdx.x;
    int t = threadIdx.x;
    float4 xv = ((const float4*)(x + (long)row * 1024))[t];
    float s = xv.x + xv.y + xv.z + xv.w;
    float s2 = xv.x * xv.x + xv.y * xv.y + xv.z * xv.z + xv.w * xv.w;
#pragma unroll
    for (int off = 32; off; off >>= 1) { s += __shfl_down(s, off, 64); s2 += __shfl_down(s2, off, 64); }
    __shared__ float ps[8];
    if ((t & 63) == 0) { ps[t >> 6] = s; ps[4 + (t >> 6)] = s2; }
    __syncthreads();
    float S = ps[0] + ps[1] + ps[2] + ps[3];
    float S2 = ps[4] + ps[5] + ps[6] + ps[7];
    float mu = S * (1.f / 1024.f);
    float var = S2 * (1.f / 1024.f) - mu * mu;
    float rstd = rsqrtf(var + 1e-5f);
    float4 gv = ((const float4*)g)[t];
    float4 bv = ((const float4*)b)[t];
    ushort4 o;
    o.x = f2bf((xv.x - mu) * rstd * gv.x + bv.x);
    o.y = f2bf((xv.y - mu) * rstd * gv.y + bv.y);
    o.z = f2bf((xv.z - mu) * rstd * gv.z + bv.z);
    o.w = f2bf((xv.w - mu) * rstd * gv.w + bv.w);
    ((ushort4*)(xn + (long)row * 1024))[t] = o;
}

// ---- m97-style GEMM: C[M,1024] = A[M,K](bf16) * Bw[1024,K]^T(bf16) * gamma + bias
// mode 0: store bf16 to head layout [B, H, Tdim, 64]
// mode 1: store fp32 = residual(fp32) + value to flat [M,1024]
__global__ __launch_bounds__(256) void gemm_bt(const u16* __restrict__ A, const u16* __restrict__ Bw,
                                               const float* __restrict__ bias,
                                               const float* __restrict__ gsum, int gidx,
                                               int K, int Tdim, u16* __restrict__ outq,
                                               const float* __restrict__ residual,
                                               float* __restrict__ outr, int mode) {
    __shared__ u16 As[128 * 32];
    __shared__ u16 Bs[128 * 32];
    int tid = threadIdx.x;
    int m0 = blockIdx.y * 128, n0 = blockIdx.x * 128;
    int w = tid >> 6, l = tid & 63, lq = l & 15, lh = l >> 4;
    int wm = (w >> 1) * 64, wn = (w & 1) * 64;
    f4x acc[4][4] = {};
    int crow = tid >> 2, cq = tid & 3;               // chunk: row=tid>>2, kchunk=tid&3 (32 k = 4x16B)
    const u16* Ag = A + (long)(m0 + crow) * K + cq * 8;
    const u16* Bg = Bw + (long)(n0 + crow) * K + cq * 8;
    char* AsB = (char*)As;
    char* BsB = (char*)Bs;
    for (int k0 = 0; k0 < K; k0 += 32) {
        __syncthreads();
        gload16(Ag + k0, AsB + tid * 16);
        gload16(Ag + k0 + (long)64 * K, AsB + 4096 + tid * 16);
        gload16(Bg + k0, BsB + tid * 16);
        gload16(Bg + k0 + (long)64 * K, BsB + 4096 + tid * 16);
        __syncthreads();
        s8x af[4], bf[4];
#pragma unroll
        for (int i = 0; i < 4; i++) {
            af[i] = *(const s8x*)&As[(wm + i * 16 + lq) * 32 + lh * 8];
            bf[i] = *(const s8x*)&Bs[(wn + i * 16 + lq) * 32 + lh * 8];
        }
#pragma unroll
        for (int i = 0; i < 4; i++)
#pragma unroll
            for (int j = 0; j < 4; j++)
                acc[i][j] = __builtin_amdgcn_mfma_f32_16x16x32_bf16(af[i], bf[j], acc[i][j], 0, 0, 0);
    }
    float gamma = gsum[gidx] * (1.0f / 1048576.0f);
#pragma unroll
    for (int i = 0; i < 4; i++) {
        int gr = m0 + wm + i * 16 + lh * 4;
#pragma unroll
        for (int j = 0; j < 4; j++) {
            int gc = n0 + wn + j * 16 + lq;
            float bb = bias[gc];
#pragma unroll
            for (int r = 0; r < 4; r++) {
                float v = acc[i][j][r] * gamma + bb;
                int row = gr + r;
                if (mode == 0) {
                    int bidx = row / Tdim, tt = row - bidx * Tdim;
                    int h = gc >> 6, d = gc & 63;
                    outq[(((long)bidx * NHEADS + h) * Tdim + tt) * 64 + d] = f2bf(v);
                } else {
                    long idx = (long)row * 1024 + gc;
                    outr[idx] = residual[idx] + v;
                }
            }
        }
    }
}

// ---- V transpose: [B,H,Tc,64] -> [B,H,64,Tc] ------------------------------
__global__ __launch_bounds__(256) void transp_k(const u16* __restrict__ v, u16* __restrict__ vt) {
    int bh = blockIdx.y, t0 = blockIdx.x * 64;
    __shared__ u16 tile[64 * 65];
    const u16* src = v + ((long)bh * TC_ + t0) * 64;
    int tid = threadIdx.x;
#pragma unroll
    for (int i = 0; i < 16; i++) {
        int e = i * 256 + tid;
        tile[(e >> 6) * 65 + (e & 63)] = src[e];
    }
    __syncthreads();
    u16* dst = vt + (long)bh * 64 * TC_ + t0;
#pragma unroll
    for (int i = 0; i < 16; i++) {
        int e = i * 256 + tid;
        int dd = e >> 6, t = e & 63;
        dst[(long)dd * TC_ + t] = tile[t * 65 + dd];
    }
}

// ---- flash attention: 64 q-rows/block, K-tiles of 64, online softmax ------
__global__ __launch_bounds__(256) void attn_k(const u16* __restrict__ qh, const u16* __restrict__ kh,
                                              const u16* __restrict__ vth, u16* __restrict__ attn) {
    __shared__ u16 Qs[64 * 64];
    __shared__ u16 Ks[64 * 64];
    __shared__ u16 Vs[64 * 64];     // transposed: [d][tk]
    __shared__ u16 Ps[4 * 16 * 64]; // per-wave P round-trip (C-layout -> A-layout)
    int tid = threadIdx.x, w = tid >> 6, l = tid & 63, lq = l & 15, lh = l >> 4;
    int bh = blockIdx.y, q0 = blockIdx.x * 64;
    const u16* qp = qh + ((long)bh * T_ + q0) * 64;
    {
        int r = tid >> 3, c = tid & 7;   // 64 rows x 8 chunks of 16B
        gload16(qp + r * 64 + c * 8, (char*)Qs + tid * 16);
        gload16(qp + (r + 32) * 64 + c * 8, (char*)Qs + 4096 + tid * 16);
    }
    __syncthreads();
    s8x qf0, qf1;
    {
        int qrow = w * 16 + lq;
        qf0 = *(const s8x*)&Qs[qrow * 64 + lh * 8];
        qf1 = *(const s8x*)&Qs[qrow * 64 + 32 + lh * 8];
    }
    f4x oacc[4] = {};
    float mrun[4], lrun[4];
#pragma unroll
    for (int r = 0; r < 4; r++) { mrun[r] = -1e30f; lrun[r] = 0.f; }
    const u16* kp = kh + (long)bh * TC_ * 64;
    const u16* vp = vth + (long)bh * 64 * TC_;
    for (int kt = 0; kt < TC_ / 64; kt++) {
        __syncthreads();
        {
            int r = tid >> 3, c = tid & 7;
            const u16* kpp = kp + kt * 64 * 64;
            gload16(kpp + r * 64 + c * 8, (char*)Ks + tid * 16);
            gload16(kpp + (r + 32) * 64 + c * 8, (char*)Ks + 4096 + tid * 16);
            const u16* vpp = vp + kt * 64;
            gload16(vpp + (long)r * TC_ + c * 8, (char*)Vs + tid * 16);
            gload16(vpp + (long)(r + 32) * TC_ + c * 8, (char*)Vs + 4096 + tid * 16);
        }
        __syncthreads();
        // S = Q * K^T (per-wave 16x64), C-layout: col=tk=lq(+16*ni), row=q=lh*4+r
        float p[4][4];
#pragma unroll
        for (int ni = 0; ni < 4; ni++) {
            s8x b0 = *(const s8x*)&Ks[(ni * 16 + lq) * 64 + lh * 8];
            s8x b1 = *(const s8x*)&Ks[(ni * 16 + lq) * 64 + 32 + lh * 8];
            f4x z = {0.f, 0.f, 0.f, 0.f};
            z = __builtin_amdgcn_mfma_f32_16x16x32_bf16(qf0, b0, z, 0, 0, 0);
            z = __builtin_amdgcn_mfma_f32_16x16x32_bf16(qf1, b1, z, 0, 0, 0);
#pragma unroll
            for (int r = 0; r < 4; r++) p[ni][r] = z[r] * SCALE_;
        }
        // online softmax per q-row (row group = 16 lanes sharing lh)
#pragma unroll
        for (int r = 0; r < 4; r++) {
            float m = fmaxf(fmaxf(p[0][r], p[1][r]), fmaxf(p[2][r], p[3][r]));
            m = fmaxf(m, __shfl_xor(m, 1));
            m = fmaxf(m, __shfl_xor(m, 2));
            m = fmaxf(m, __shfl_xor(m, 4));
            m = fmaxf(m, __shfl_xor(m, 8));
            float mn = fmaxf(mrun[r], m);
            float al = __expf(mrun[r] - mn);
            mrun[r] = mn;
            float rs = 0.f;
#pragma unroll
            for (int ni = 0; ni < 4; ni++) { p[ni][r] = __expf(p[ni][r] - mn); rs += p[ni][r]; }
            rs += __shfl_xor(rs, 1);
            rs += __shfl_xor(rs, 2);
            rs += __shfl_xor(rs, 4);
            rs += __shfl_xor(rs, 8);
            lrun[r] = lrun[r] * al + rs;
#pragma unroll
            for (int nd = 0; nd < 4; nd++) oacc[nd][r] *= al;
        }
        // P: C-layout regs -> LDS -> A-layout frags (m120-verified transform)
        u16* pw = &Ps[w * 1024];
#pragma unroll
        for (int ni = 0; ni < 4; ni++)
#pragma unroll
            for (int r = 0; r < 4; r++)
                pw[(lh * 4 + r) * 64 + ni * 16 + lq] = f2bf(p[ni][r]);
        __syncthreads();
        s8x pf0 = *(const s8x*)&pw[lq * 64 + lh * 8];
        s8x pf1 = *(const s8x*)&pw[lq * 64 + 32 + lh * 8];
#pragma unroll
        for (int nd = 0; nd < 4; nd++) {
            s8x v0 = *(const s8x*)&Vs[(nd * 16 + lq) * 64 + lh * 8];
            s8x v1 = *(const s8x*)&Vs[(nd * 16 + lq) * 64 + 32 + lh * 8];
            oacc[nd] = __builtin_amdgcn_mfma_f32_16x16x32_bf16(pf0, v0, oacc[nd], 0, 0, 0);
            oacc[nd] = __builtin_amdgcn_mfma_f32_16x16x32_bf16(pf1, v1, oacc[nd], 0, 0, 0);
        }
    }
    int b = bh >> 4, h = bh & 15;
#pragma unroll
    for (int r = 0; r < 4; r++) {
        int q = q0 + w * 16 + lh * 4 + r;
        float rcp = 1.f / lrun[r];
#pragma unroll
        for (int nd = 0; nd < 4; nd++)
            attn[((long)(b * T_ + q)) * 1024 + h * 64 + nd * 16 + lq] = f2bf(oacc[nd][r] * rcp);
    }
}

extern "C" void kernel_launch(void* const* d_in, const int* in_sizes, int n_in,
                              void* d_out, int out_size, void* d_ws, size_t ws_size,
                              hipStream_t stream) {
    const float* x   = (const float*)d_in[0];
    const float* ctx = (const float*)d_in[1];
    const float* Wq  = (const float*)d_in[2];
    const float* bq  = (const float*)d_in[3];
    const float* Wk  = (const float*)d_in[4];
    const float* bk  = (const float*)d_in[5];
    const float* Wv  = (const float*)d_in[6];
    const float* bv  = (const float*)d_in[7];
    const float* Wo  = (const float*)d_in[8];
    const float* bo  = (const float*)d_in[9];
    const float* lng = (const float*)d_in[10];
    const float* lnb = (const float*)d_in[11];
    float* out = (float*)d_out;

    char* ws = (char*)d_ws;
    float* gsum = (float*)ws;
    size_t off = 256;
    u16* wt[4];
    for (int i = 0; i < 4; i++) { wt[i] = (u16*)(ws + off); off += (size_t)1024 * 1024 * 2; }
    u16* ctxb = (u16*)(ws + off); off += (size_t)8192 * 1024 * 2;
    u16* xn  = (u16*)(ws + off); off += (size_t)4096 * 1024 * 2;   // later reused as attn
    u16* qb  = (u16*)(ws + off); off += (size_t)4096 * 1024 * 2;
    u16* kb  = (u16*)(ws + off); off += (size_t)8192 * 1024 * 2;
    u16* vb  = (u16*)(ws + off); off += (size_t)8192 * 1024 * 2;
    u16* vtb = (u16*)(ws + off); off += (size_t)8192 * 1024 * 2;   // total ~88MB
    u16* attn = xn;  // xn dead after q-gemm; alias

    hipMemsetAsync(gsum, 0, 16, stream);
    const float* Ws4[4] = {Wq, Wk, Wv, Wo};
    for (int i = 0; i < 4; i++) absmean_k<<<256, 256, 0, stream>>>(Ws4[i], gsum, i);
    for (int i = 0; i < 4; i++) quant_k<<<1024, 256, 0, stream>>>(Ws4[i], wt[i], gsum, i);
    ln_k<<<4096, 256, 0, stream>>>(x, lng, lnb, xn);
    cast_k<<<8192, 256, 0, stream>>>(ctx, ctxb);   // 8M elems, 4/thread
    // q = LN(x) @ WqT  -> [B,H,T,64]
    gemm_bt<<<dim3(8, 32), 256, 0, stream>>>(xn, wt[0], bq, gsum, 0, 1024, 1024, qb, nullptr, nullptr, 0);
    // k,v = ctx @ W{k,v}T -> [B,H,Tc,64]
    gemm_bt<<<dim3(8, 64), 256, 0, stream>>>(ctxb, wt[1], bk, gsum, 1, 1024, 2048, kb, nullptr, nullptr, 0);
    gemm_bt<<<dim3(8, 64), 256, 0, stream>>>(ctxb, wt[2], bv, gsum, 2, 1024, 2048, vb, nullptr, nullptr, 0);
    transp_k<<<dim3(32, 64), 256, 0, stream>>>(vb, vtb);
    attn_k<<<dim3(16, 64), 256, 0, stream>>>(qb, kb, vtb, attn);
    // out = x + attn @ WoT
    gemm_bt<<<dim3(8, 32), 256, 0, stream>>>(attn, wt[3], bo, gsum, 3, 1024, 1024, nullptr, x, out, 1);
}

// Round 3
// 358.560 us; speedup vs baseline: 1.2969x; 1.2969x over previous
//
#include <hip/hip_runtime.h>
#include <hip/hip_bf16.h>

typedef __attribute__((ext_vector_type(8))) short s8x;   // 8 bf16 = 4 VGPRs (MFMA A/B frag)
typedef __attribute__((ext_vector_type(4))) float f4x;   // MFMA C/D frag
typedef unsigned short u16;
typedef unsigned int u32;

#define NHEADS 16
#define T_ 1024
#define TC_ 2048

__device__ __forceinline__ u16 f2bf(float f) {
    u32 u = __float_as_uint(f);
    return (u16)((u + 0x7fffu + ((u >> 16) & 1u)) >> 16);  // RNE
}

// async global->LDS, 16B per lane; LDS dst is wave-uniform base + lane*16
__device__ __forceinline__ void gload16(const void* g, void* l) {
    __builtin_amdgcn_global_load_lds((const __attribute__((address_space(1))) u32*)g,
                                     (__attribute__((address_space(3))) u32*)l, 16, 0, 0);
}

// ---- gamma = mean(|W|), 4 weights in one launch ----------------------------
__global__ __launch_bounds__(256) void absmean_k(const float* __restrict__ W0, const float* __restrict__ W1,
                                                 const float* __restrict__ W2, const float* __restrict__ W3,
                                                 float* __restrict__ gsum) {
    int wi = blockIdx.y;
    const float* W = (wi == 0) ? W0 : (wi == 1) ? W1 : (wi == 2) ? W2 : W3;
    const int n4 = (1024 * 1024) / 4;
    float s = 0.f;
    int stride = gridDim.x * blockDim.x;
    for (int i = blockIdx.x * blockDim.x + threadIdx.x; i < n4; i += stride) {
        float4 v = ((const float4*)W)[i];
        s += fabsf(v.x) + fabsf(v.y) + fabsf(v.z) + fabsf(v.w);
    }
#pragma unroll
    for (int off = 32; off; off >>= 1) s += __shfl_down(s, off, 64);
    __shared__ float ps[4];
    if ((threadIdx.x & 63) == 0) ps[threadIdx.x >> 6] = s;
    __syncthreads();
    if (threadIdx.x == 0) atomicAdd(gsum + wi, ps[0] + ps[1] + ps[2] + ps[3]);
}

// ---- ternary quantize, 4 weights in one launch -----------------------------
__global__ __launch_bounds__(256) void quant_k(const float* __restrict__ W0, const float* __restrict__ W1,
                                               const float* __restrict__ W2, const float* __restrict__ W3,
                                               u16* __restrict__ D0, u16* __restrict__ D1,
                                               u16* __restrict__ D2, u16* __restrict__ D3,
                                               const float* __restrict__ gsum) {
    int wi = blockIdx.y;
    const float* W = (wi == 0) ? W0 : (wi == 1) ? W1 : (wi == 2) ? W2 : W3;
    u16* D = (wi == 0) ? D0 : (wi == 1) ? D1 : (wi == 2) ? D2 : D3;
    float gamma = gsum[wi] * (1.0f / 1048576.0f);
    float inv = 1.0f / (gamma + 1e-5f);
    int i = blockIdx.x * 256 + threadIdx.x;
    float4 w = ((const float4*)W)[i];
    ushort4 o;
    o.x = f2bf(fminf(1.f, fmaxf(-1.f, rintf(w.x * inv))));
    o.y = f2bf(fminf(1.f, fmaxf(-1.f, rintf(w.y * inv))));
    o.z = f2bf(fminf(1.f, fmaxf(-1.f, rintf(w.z * inv))));
    o.w = f2bf(fminf(1.f, fmaxf(-1.f, rintf(w.w * inv))));
    ((ushort4*)D)[i] = o;
}

// ---- fp32 -> bf16 cast (context) ------------------------------------------
__global__ __launch_bounds__(256) void cast_k(const float* __restrict__ src, u16* __restrict__ dst) {
    int i = blockIdx.x * 256 + threadIdx.x;
    float4 v = ((const float4*)src)[i];
    ushort4 o = {f2bf(v.x), f2bf(v.y), f2bf(v.z), f2bf(v.w)};
    ((ushort4*)dst)[i] = o;
}

// ---- LayerNorm(x fp32) -> bf16, one block per row of 1024 -----------------
__global__ __launch_bounds__(256) void ln_k(const float* __restrict__ x, const float* __restrict__ g,
                                            const float* __restrict__ b, u16* __restrict__ xn) {
    int row = blockIdx.x;
    int t = threadIdx.x;
    float4 xv = ((const float4*)(x + (long)row * 1024))[t];
    float s = xv.x + xv.y + xv.z + xv.w;
    float s2 = xv.x * xv.x + xv.y * xv.y + xv.z * xv.z + xv.w * xv.w;
#pragma unroll
    for (int off = 32; off; off >>= 1) { s += __shfl_down(s, off, 64); s2 += __shfl_down(s2, off, 64); }
    __shared__ float ps[8];
    if ((t & 63) == 0) { ps[t >> 6] = s; ps[4 + (t >> 6)] = s2; }
    __syncthreads();
    float S = ps[0] + ps[1] + ps[2] + ps[3];
    float S2 = ps[4] + ps[5] + ps[6] + ps[7];
    float mu = S * (1.f / 1024.f);
    float var = S2 * (1.f / 1024.f) - mu * mu;
    float rstd = rsqrtf(var + 1e-5f);
    float4 gv = ((const float4*)g)[t];
    float4 bv = ((const float4*)b)[t];
    ushort4 o;
    o.x = f2bf((xv.x - mu) * rstd * gv.x + bv.x);
    o.y = f2bf((xv.y - mu) * rstd * gv.y + bv.y);
    o.z = f2bf((xv.z - mu) * rstd * gv.z + bv.z);
    o.w = f2bf((xv.w - mu) * rstd * gv.w + bv.w);
    ((ushort4*)(xn + (long)row * 1024))[t] = o;
}

// ---- GEMM: C[M,N] = A[M,K](bf16) @ Bw[N,K]^T(ternary bf16) * gamma*sc + bias*sc
// grid (M/128, N/128)  [m-tile on blockIdx.x for XCD L2 locality]
// mode 0: bf16 head-layout scatter; cols >= nsplit go to outB with biasB/gB
// mode 1: fp32 residual + value, flat [M,1024]
__global__ __launch_bounds__(256) void gemm_bt(const u16* __restrict__ A, const u16* __restrict__ Bw,
                                               const float* __restrict__ biasA, const float* __restrict__ biasB,
                                               const float* __restrict__ gsum, int gA, int gB, int nsplit,
                                               int K, int Tdim, u16* __restrict__ outA, u16* __restrict__ outB,
                                               const float* __restrict__ residual,
                                               float* __restrict__ outr, int mode, float sc) {
    __shared__ u16 As[128 * 32];
    __shared__ u16 Bs[128 * 32];
    int tid = threadIdx.x;
    int m0 = blockIdx.x * 128, n0 = blockIdx.y * 128;
    int w = tid >> 6, l = tid & 63, lq = l & 15, lh = l >> 4;
    int wm = (w >> 1) * 64, wn = (w & 1) * 64;
    f4x acc[4][4] = {};
    int crow = tid >> 2, cq = tid & 3;               // chunk: row=tid>>2, kchunk=tid&3 (32 k = 4x16B)
    const u16* Ag = A + (long)(m0 + crow) * K + cq * 8;
    const u16* Bg = Bw + (long)(n0 + crow) * K + cq * 8;
    char* AsB = (char*)As;
    char* BsB = (char*)Bs;
    for (int k0 = 0; k0 < K; k0 += 32) {
        __syncthreads();
        gload16(Ag + k0, AsB + tid * 16);
        gload16(Ag + k0 + (long)64 * K, AsB + 4096 + tid * 16);
        gload16(Bg + k0, BsB + tid * 16);
        gload16(Bg + k0 + (long)64 * K, BsB + 4096 + tid * 16);
        __syncthreads();
        s8x af[4], bf[4];
#pragma unroll
        for (int i = 0; i < 4; i++) {
            af[i] = *(const s8x*)&As[(wm + i * 16 + lq) * 32 + lh * 8];
            bf[i] = *(const s8x*)&Bs[(wn + i * 16 + lq) * 32 + lh * 8];
        }
#pragma unroll
        for (int i = 0; i < 4; i++)
#pragma unroll
            for (int j = 0; j < 4; j++)
                acc[i][j] = __builtin_amdgcn_mfma_f32_16x16x32_bf16(af[i], bf[j], acc[i][j], 0, 0, 0);
    }
    bool second = (n0 >= nsplit);
    const float* bias = second ? biasB : biasA;
    u16* outq = second ? outB : outA;
    int nbase = n0 - (second ? nsplit : 0);
    float gamma = gsum[second ? gB : gA] * (1.0f / 1048576.0f) * sc;
#pragma unroll
    for (int i = 0; i < 4; i++) {
        int gr = m0 + wm + i * 16 + lh * 4;
#pragma unroll
        for (int j = 0; j < 4; j++) {
            int gc = nbase + wn + j * 16 + lq;
            float bb = bias[gc] * sc;
#pragma unroll
            for (int r = 0; r < 4; r++) {
                float v = acc[i][j][r] * gamma + bb;
                int row = gr + r;
                if (mode == 0) {
                    int bidx = row / Tdim, tt = row - bidx * Tdim;
                    int h = gc >> 6, d = gc & 63;
                    outq[(((long)bidx * NHEADS + h) * Tdim + tt) * 64 + d] = f2bf(v);
                } else {
                    long idx = (long)row * 1024 + gc;
                    outr[idx] = residual[idx] + v;
                }
            }
        }
    }
}

// ---- V transpose: [B,H,Tc,64] -> [B,H,64,Tc] ------------------------------
__global__ __launch_bounds__(256) void transp_k(const u16* __restrict__ v, u16* __restrict__ vt) {
    int bh = blockIdx.y, t0 = blockIdx.x * 64;
    __shared__ u16 tile[64 * 65];
    const u16* src = v + ((long)bh * TC_ + t0) * 64;
    int tid = threadIdx.x;
#pragma unroll
    for (int i = 0; i < 16; i++) {
        int e = i * 256 + tid;
        tile[(e >> 6) * 65 + (e & 63)] = src[e];
    }
    __syncthreads();
    u16* dst = vt + (long)bh * 64 * TC_ + t0;
#pragma unroll
    for (int i = 0; i < 16; i++) {
        int e = i * 256 + tid;
        int dd = e >> 6, t = e & 63;
        dst[(long)dd * TC_ + t] = tile[t * 65 + dd];
    }
}

// ---- flash attention v2: 128 q/block (32/wave), K-tile 64, single barrier,
//      double-buffered K/V, XOR-swizzled LDS, tile-max, MFMA row-sums --------
// grid (64 bh, 8 q-tiles); SCALE is pre-folded into q.
__global__ __launch_bounds__(256) void attn_k(const u16* __restrict__ qh, const u16* __restrict__ kh,
                                              const u16* __restrict__ vth, u16* __restrict__ attn) {
    // LDS map: [0,16K) KV buf0 (Ks 8K | Vs 8K), [16K,32K) KV buf1, [32K,50K) P (4 waves x 32 x 72 u16)
    // Q staged transiently in [0,16K).
    __shared__ __align__(16) char smem[51200];
    int tid = threadIdx.x, w = tid >> 6, l = tid & 63, lq = l & 15, lh = l >> 4;
    int bh = blockIdx.x, q0 = blockIdx.y * 128;
    const u16* qp = qh + ((long)bh * T_ + q0) * 64;
    const u16* kp = kh + (long)bh * TC_ * 64;
    const u16* vp = vth + (long)bh * 64 * TC_;
    // stage Q (swizzled: LDS slot cs holds global chunk cs^(row&7))
#pragma unroll
    for (int i = 0; i < 4; i++) {
        int cid = i * 256 + tid;
        int r = cid >> 3, c = (cid & 7) ^ (r & 7);
        gload16(qp + r * 64 + c * 8, smem + cid * 16);
    }
    __syncthreads();
    s8x qf[2][2];   // B-operand: Q[q=w*32+nb*16+lq][d = dh*32 + lh*8 + j]
#pragma unroll
    for (int nb = 0; nb < 2; nb++)
#pragma unroll
        for (int dh = 0; dh < 2; dh++) {
            int qrow = w * 32 + nb * 16 + lq;
            int ch = (dh * 4 + lh) ^ (qrow & 7);
            qf[nb][dh] = *(const s8x*)(smem + qrow * 128 + ch * 16);
        }
    __syncthreads();   // Q region about to be overwritten by KV buf0
    // stage K/V tile kt into buffer buf
#define STAGE_KV(kt, buf)                                                          \
    {                                                                              \
        char* Kb = smem + (buf) * 16384;                                           \
        char* Vb = Kb + 8192;                                                      \
        _Pragma("unroll") for (int i = 0; i < 2; i++) {                            \
            int cid = i * 256 + tid;                                               \
            int r = cid >> 3, c = (cid & 7) ^ (r & 7);                             \
            gload16(kp + ((kt) * 64 + r) * 64 + c * 8, Kb + cid * 16);             \
            gload16(vp + (long)r * TC_ + (kt) * 64 + c * 8, Vb + cid * 16);        \
        }                                                                          \
    }
    STAGE_KV(0, 0);
    f4x oacc[2][4] = {};
    f4x lrun[2] = {};
    float mrun = -1e30f;
    const s8x ones = {16256, 16256, 16256, 16256, 16256, 16256, 16256, 16256};  // bf16 1.0 x8
    char* Psb = smem + 32768 + w * 4608;   // per-wave P: 32 rows x 72 u16 (pad -> conflict-free)
    for (int kt = 0; kt < TC_ / 64; kt++) {
        __syncthreads();                     // drains vmcnt -> tile kt visible; protects buf reuse
        if (kt + 1 < TC_ / 64) STAGE_KV(kt + 1, (kt + 1) & 1);   // prefetch overlaps compute
        char* Ksb = smem + (kt & 1) * 16384;
        char* Vsb = Ksb + 8192;
        // S^T = K Q^T : rows = k (ni*16 + lh*4 + r), cols = q (nb*16 + lq)
        f4x z[2][4];
#pragma unroll
        for (int ni = 0; ni < 4; ni++) {
            int kr = ni * 16 + lq;
            s8x a0 = *(const s8x*)(Ksb + kr * 128 + ((lh) ^ (kr & 7)) * 16);
            s8x a1 = *(const s8x*)(Ksb + kr * 128 + ((4 + lh) ^ (kr & 7)) * 16);
#pragma unroll
            for (int nb = 0; nb < 2; nb++) {
                f4x zz = {0.f, 0.f, 0.f, 0.f};
                zz = __builtin_amdgcn_mfma_f32_16x16x32_bf16(a0, qf[nb][0], zz, 0, 0, 0);
                zz = __builtin_amdgcn_mfma_f32_16x16x32_bf16(a1, qf[nb][1], zz, 0, 0, 0);
                z[nb][ni] = zz;
            }
        }
        // tile-wide max (upper bound per row -> exact online softmax, m cancels)
        float mx = -1e30f;
#pragma unroll
        for (int nb = 0; nb < 2; nb++)
#pragma unroll
            for (int ni = 0; ni < 4; ni++)
#pragma unroll
                for (int r = 0; r < 4; r++) mx = fmaxf(mx, z[nb][ni][r]);
#pragma unroll
        for (int s = 1; s <= 32; s <<= 1) mx = fmaxf(mx, __shfl_xor(mx, s));
        float mn = fmaxf(mrun, mx);
        float al = __expf(mrun - mn);
        mrun = mn;
        // P = exp(S - m) -> LDS [q][k] (A-layout ready), packed b64 writes
#pragma unroll
        for (int nb = 0; nb < 2; nb++) {
            int prow = nb * 16 + lq;
#pragma unroll
            for (int ni = 0; ni < 4; ni++) {
                ushort4 pk;
                pk.x = f2bf(__expf(z[nb][ni][0] - mn));
                pk.y = f2bf(__expf(z[nb][ni][1] - mn));
                pk.z = f2bf(__expf(z[nb][ni][2] - mn));
                pk.w = f2bf(__expf(z[nb][ni][3] - mn));
                *(ushort4*)(Psb + prow * 144 + ni * 32 + lh * 8) = pk;
            }
        }
        // rescale running state
#pragma unroll
        for (int qb = 0; qb < 2; qb++)
#pragma unroll
            for (int nd = 0; nd < 4; nd++)
#pragma unroll
                for (int r = 0; r < 4; r++) oacc[qb][nd][r] *= al;
        // V frags (B-operand), shared across both q-blocks
        s8x vf[4][2];
#pragma unroll
        for (int nd = 0; nd < 4; nd++) {
            int vr = nd * 16 + lq;
            vf[nd][0] = *(const s8x*)(Vsb + vr * 128 + ((lh) ^ (vr & 7)) * 16);
            vf[nd][1] = *(const s8x*)(Vsb + vr * 128 + ((4 + lh) ^ (vr & 7)) * 16);
        }
#pragma unroll
        for (int qb = 0; qb < 2; qb++) {
            int prow = qb * 16 + lq;
            s8x pf0 = *(const s8x*)(Psb + prow * 144 + lh * 16);
            s8x pf1 = *(const s8x*)(Psb + prow * 144 + 64 + lh * 16);
            f4x rs = {0.f, 0.f, 0.f, 0.f};   // row sums via ones-MFMA (lands in oacc row layout)
            rs = __builtin_amdgcn_mfma_f32_16x16x32_bf16(pf0, ones, rs, 0, 0, 0);
            rs = __builtin_amdgcn_mfma_f32_16x16x32_bf16(pf1, ones, rs, 0, 0, 0);
#pragma unroll
            for (int r = 0; r < 4; r++) lrun[qb][r] = lrun[qb][r] * al + rs[r];
#pragma unroll
            for (int nd = 0; nd < 4; nd++) {
                oacc[qb][nd] = __builtin_amdgcn_mfma_f32_16x16x32_bf16(pf0, vf[nd][0], oacc[qb][nd], 0, 0, 0);
                oacc[qb][nd] = __builtin_amdgcn_mfma_f32_16x16x32_bf16(pf1, vf[nd][1], oacc[qb][nd], 0, 0, 0);
            }
        }
    }
    int b = bh >> 4, h = bh & 15;
#pragma unroll
    for (int qb = 0; qb < 2; qb++)
#pragma unroll
        for (int r = 0; r < 4; r++) {
            int q = q0 + w * 32 + qb * 16 + lh * 4 + r;
            float rcp = 1.f / lrun[qb][r];
#pragma unroll
            for (int nd = 0; nd < 4; nd++)
                attn[((long)(b * T_ + q)) * 1024 + h * 64 + nd * 16 + lq] = f2bf(oacc[qb][nd][r] * rcp);
        }
}

extern "C" void kernel_launch(void* const* d_in, const int* in_sizes, int n_in,
                              void* d_out, int out_size, void* d_ws, size_t ws_size,
                              hipStream_t stream) {
    const float* x   = (const float*)d_in[0];
    const float* ctx = (const float*)d_in[1];
    const float* Wq  = (const float*)d_in[2];
    const float* bq  = (const float*)d_in[3];
    const float* Wk  = (const float*)d_in[4];
    const float* bk  = (const float*)d_in[5];
    const float* Wv  = (const float*)d_in[6];
    const float* bv  = (const float*)d_in[7];
    const float* Wo  = (const float*)d_in[8];
    const float* bo  = (const float*)d_in[9];
    const float* lng = (const float*)d_in[10];
    const float* lnb = (const float*)d_in[11];
    float* out = (float*)d_out;

    char* ws = (char*)d_ws;
    float* gsum = (float*)ws;
    size_t off = 256;
    u16* wtq  = (u16*)(ws + off); off += (size_t)1024 * 1024 * 2;
    u16* wtkv = (u16*)(ws + off); off += (size_t)2048 * 1024 * 2;   // [Wk; Wv] ternary
    u16* wto  = (u16*)(ws + off); off += (size_t)1024 * 1024 * 2;
    u16* ctxb = (u16*)(ws + off); off += (size_t)8192 * 1024 * 2;
    u16* xn   = (u16*)(ws + off); off += (size_t)4096 * 1024 * 2;   // reused as attn
    u16* qb_  = (u16*)(ws + off); off += (size_t)4096 * 1024 * 2;
    u16* kb   = (u16*)(ws + off); off += (size_t)8192 * 1024 * 2;
    u16* vb   = (u16*)(ws + off); off += (size_t)8192 * 1024 * 2;
    u16* vtb  = (u16*)(ws + off); off += (size_t)8192 * 1024 * 2;   // ~88MB
    u16* attnb = xn;  // xn dead after q-gemm

    hipMemsetAsync(gsum, 0, 16, stream);
    absmean_k<<<dim3(128, 4), 256, 0, stream>>>(Wq, Wk, Wv, Wo, gsum);
    quant_k<<<dim3(1024, 4), 256, 0, stream>>>(Wq, Wk, Wv, Wo,
                                               wtq, wtkv, wtkv + (size_t)1024 * 1024, wto, gsum);
    ln_k<<<4096, 256, 0, stream>>>(x, lng, lnb, xn);
    cast_k<<<8192, 256, 0, stream>>>(ctx, ctxb);
    // q = LN(x) @ WqT * scale -> [B,H,T,64]   (softmax scale folded here)
    gemm_bt<<<dim3(32, 8), 256, 0, stream>>>(xn, wtq, bq, bq, gsum, 0, 0, 4096,
                                             1024, 1024, qb_, qb_, nullptr, nullptr, 0, 0.125f);
    // k|v = ctx @ [Wk;Wv]T -> [B,H,Tc,64] each (fused, split at col 1024)
    gemm_bt<<<dim3(64, 16), 256, 0, stream>>>(ctxb, wtkv, bk, bv, gsum, 1, 2, 1024,
                                              1024, 2048, kb, vb, nullptr, nullptr, 0, 1.0f);
    transp_k<<<dim3(32, 64), 256, 0, stream>>>(vb, vtb);
    attn_k<<<dim3(64, 8), 256, 0, stream>>>(qb_, kb, vtb, attnb);
    // out = x + attn @ WoT
    gemm_bt<<<dim3(32, 8), 256, 0, stream>>>(attnb, wto, bo, bo, gsum, 3, 3, 4096,
                                             1024, 1024, nullptr, nullptr, x, out, 1, 1.0f);
}

// Round 4
// 281.780 us; speedup vs baseline: 1.6503x; 1.2725x over previous
//
#include <hip/hip_runtime.h>
#include <hip/hip_bf16.h>

typedef __attribute__((ext_vector_type(8))) short s8x;   // 8 bf16 = 4 VGPRs (MFMA A/B frag)
typedef __attribute__((ext_vector_type(4))) float f4x;   // MFMA C/D frag
typedef unsigned short u16;
typedef unsigned int u32;

#define T_ 1024
#define TC_ 2048

__device__ __forceinline__ u16 f2bf(float f) {
    u32 u = __float_as_uint(f);
    return (u16)((u + 0x7fffu + ((u >> 16) & 1u)) >> 16);  // RNE
}

#if defined(__has_builtin)
#if __has_builtin(__builtin_amdgcn_cvt_pk_bf16_f32)
#define HAVE_PK 1
#endif
#endif

// pack two fp32 -> two bf16 (RNE) in one u32; HW packed cvt when available
__device__ __forceinline__ u32 pack2bf(float a, float b) {
#ifdef HAVE_PK
    typedef __attribute__((ext_vector_type(2))) __bf16 bf2t;
    bf2t r = __builtin_amdgcn_cvt_pk_bf16_f32(a, b);
    u32 u;
    __builtin_memcpy(&u, &r, 4);
    return u;
#else
    return (u32)f2bf(a) | ((u32)f2bf(b) << 16);
#endif
}

// async global->LDS, 16B per lane; LDS dst is wave-uniform base + lane*16
__device__ __forceinline__ void gload16(const void* g, void* l) {
    __builtin_amdgcn_global_load_lds((const __attribute__((address_space(1))) u32*)g,
                                     (__attribute__((address_space(3))) u32*)l, 16, 0, 0);
}

// ---- gamma = mean(|W|), 4 weights in one launch ----------------------------
__global__ __launch_bounds__(256) void absmean_k(const float* __restrict__ W0, const float* __restrict__ W1,
                                                 const float* __restrict__ W2, const float* __restrict__ W3,
                                                 float* __restrict__ gsum) {
    int wi = blockIdx.y;
    const float* W = (wi == 0) ? W0 : (wi == 1) ? W1 : (wi == 2) ? W2 : W3;
    const int n4 = (1024 * 1024) / 4;
    float s = 0.f;
    int stride = gridDim.x * blockDim.x;
    for (int i = blockIdx.x * blockDim.x + threadIdx.x; i < n4; i += stride) {
        float4 v = ((const float4*)W)[i];
        s += fabsf(v.x) + fabsf(v.y) + fabsf(v.z) + fabsf(v.w);
    }
#pragma unroll
    for (int off = 32; off; off >>= 1) s += __shfl_down(s, off, 64);
    __shared__ float ps[4];
    if ((threadIdx.x & 63) == 0) ps[threadIdx.x >> 6] = s;
    __syncthreads();
    if (threadIdx.x == 0) atomicAdd(gsum + wi, ps[0] + ps[1] + ps[2] + ps[3]);
}

// ---- merged prep: LN(x)->xn | ctx->bf16 | ternary quantize (one launch) ----
__global__ __launch_bounds__(256) void prep_k(
        const float* __restrict__ x, const float* __restrict__ lng, const float* __restrict__ lnb,
        u16* __restrict__ xn,
        const float* __restrict__ ctx, u16* __restrict__ ctxb,
        const float* __restrict__ W0, const float* __restrict__ W1,
        const float* __restrict__ W2, const float* __restrict__ W3,
        u16* __restrict__ D0, u16* __restrict__ D1, u16* __restrict__ D2, u16* __restrict__ D3,
        const float* __restrict__ gsum) {
    __shared__ float ps[8];
    int bx = blockIdx.x, t = threadIdx.x;
    if (bx < 4096) {                      // LayerNorm row bx
        int row = bx;
        float4 xv = ((const float4*)(x + (long)row * 1024))[t];
        float s = xv.x + xv.y + xv.z + xv.w;
        float s2 = xv.x * xv.x + xv.y * xv.y + xv.z * xv.z + xv.w * xv.w;
#pragma unroll
        for (int off = 32; off; off >>= 1) { s += __shfl_down(s, off, 64); s2 += __shfl_down(s2, off, 64); }
        if ((t & 63) == 0) { ps[t >> 6] = s; ps[4 + (t >> 6)] = s2; }
        __syncthreads();
        float S = ps[0] + ps[1] + ps[2] + ps[3];
        float S2 = ps[4] + ps[5] + ps[6] + ps[7];
        float mu = S * (1.f / 1024.f);
        float var = S2 * (1.f / 1024.f) - mu * mu;
        float rstd = rsqrtf(var + 1e-5f);
        float4 gv = ((const float4*)lng)[t];
        float4 bv = ((const float4*)lnb)[t];
        uint2 o;
        o.x = pack2bf((xv.x - mu) * rstd * gv.x + bv.x, (xv.y - mu) * rstd * gv.y + bv.y);
        o.y = pack2bf((xv.z - mu) * rstd * gv.z + bv.z, (xv.w - mu) * rstd * gv.w + bv.w);
        ((uint2*)(xn + (long)row * 1024))[t] = o;
    } else if (bx < 12288) {              // cast context
        int i = (bx - 4096) * 256 + t;
        float4 v = ((const float4*)ctx)[i];
        uint2 o = {pack2bf(v.x, v.y), pack2bf(v.z, v.w)};
        ((uint2*)ctxb)[i] = o;
    } else {                              // ternary quantize
        int wi = (bx - 12288) >> 10;
        const float* W = (wi == 0) ? W0 : (wi == 1) ? W1 : (wi == 2) ? W2 : W3;
        u16* D = (wi == 0) ? D0 : (wi == 1) ? D1 : (wi == 2) ? D2 : D3;
        float inv = 1.0f / (gsum[wi] * (1.0f / 1048576.0f) + 1e-5f);
        int i = ((bx - 12288) & 1023) * 256 + t;
        float4 wv = ((const float4*)W)[i];
        uint2 o;
        o.x = pack2bf(fminf(1.f, fmaxf(-1.f, rintf(wv.x * inv))),
                      fminf(1.f, fmaxf(-1.f, rintf(wv.y * inv))));
        o.y = pack2bf(fminf(1.f, fmaxf(-1.f, rintf(wv.z * inv))),
                      fminf(1.f, fmaxf(-1.f, rintf(wv.w * inv))));
        ((uint2*)D)[i] = o;
    }
}

// ---- uber GEMM: q (256 blk) | k (512 blk) | v^T (512 blk), BK=64, swizzled LDS
// prob0: qb = xn @ WqT * 0.125, head scatter [B,16,1024,64]
// prob1: kb = ctx @ WkT, head scatter [B,16,2048,64]
// prob2: vtb = (ctx @ WvT)^T via LDS transpose -> [B,16,64,2048] coalesced b128 stores
__global__ __launch_bounds__(256) void gemm_fused(
        const u16* __restrict__ xn, const u16* __restrict__ ctxb,
        const u16* __restrict__ wtq, const u16* __restrict__ wtk, const u16* __restrict__ wtv,
        const float* __restrict__ bq, const float* __restrict__ bk, const float* __restrict__ bv,
        const float* __restrict__ gsum,
        u16* __restrict__ qb, u16* __restrict__ kb, u16* __restrict__ vtb) {
    __shared__ __align__(16) char smem[32768];   // As 16K | Bs 16K; reused as 32K C^T tile (prob2)
    int tid = threadIdx.x;
    int w = tid >> 6, l = tid & 63, lq = l & 15, lh = l >> 4;
    int wm = (w >> 1) * 64, wn = (w & 1) * 64;
    int bx = blockIdx.x;
    int prob; const u16 *A, *Wt; const float* bias; int tshift; float sc; int gidx;
    if (bx < 256)      { prob = 0;            A = xn;   Wt = wtq; bias = bq; tshift = 10; sc = 0.125f; gidx = 0; }
    else if (bx < 768) { prob = 1; bx -= 256; A = ctxb; Wt = wtk; bias = bk; tshift = 11; sc = 1.0f;  gidx = 1; }
    else               { prob = 2; bx -= 768; A = ctxb; Wt = wtv; bias = bv; tshift = 11; sc = 1.0f;  gidx = 2; }
    int m0 = (bx >> 3) * 128, n0 = (bx & 7) * 128;
    char* AsB = smem;
    char* BsB = smem + 16384;
    f4x acc[4][4] = {};
    int rb = tid >> 3;                       // staging row base (within 32-row group)
    int cg = (tid & 7) ^ (rb & 7);           // swizzled source chunk for this lane's LDS slot
    const u16* Ag = A + (long)m0 * 1024 + cg * 8;
    const u16* Bg = Wt + (long)n0 * 1024 + cg * 8;
    for (int k0 = 0; k0 < 1024; k0 += 64) {
        __syncthreads();
#pragma unroll
        for (int i = 0; i < 4; i++) {
            gload16(Ag + (long)(i * 32 + rb) * 1024 + k0, AsB + (i * 256 + tid) * 16);
            gload16(Bg + (long)(i * 32 + rb) * 1024 + k0, BsB + (i * 256 + tid) * 16);
        }
        __syncthreads();
#pragma unroll
        for (int s = 0; s < 2; s++) {
            int sl = (s * 4 + lh) ^ (lq & 7);
            s8x af[4], bfr[4];
#pragma unroll
            for (int i = 0; i < 4; i++) {
                af[i] = *(const s8x*)(AsB + (wm + i * 16 + lq) * 128 + sl * 16);
                bfr[i] = *(const s8x*)(BsB + (wn + i * 16 + lq) * 128 + sl * 16);
            }
#pragma unroll
            for (int i = 0; i < 4; i++)
#pragma unroll
                for (int j = 0; j < 4; j++)
                    acc[i][j] = __builtin_amdgcn_mfma_f32_16x16x32_bf16(af[i], bfr[j], acc[i][j], 0, 0, 0);
        }
    }
    float gamma = gsum[gidx] * (1.0f / 1048576.0f) * sc;
    if (prob < 2) {
        u16* outq = (prob == 0) ? qb : kb;
        int tmask = (1 << tshift) - 1;
#pragma unroll
        for (int i = 0; i < 4; i++) {
            int gr = m0 + wm + i * 16 + lh * 4;
#pragma unroll
            for (int j = 0; j < 4; j++) {
                int gc = n0 + wn + j * 16 + lq;
                float bb = bias[gc] * sc;
                int h = gc >> 6, d = gc & 63;
#pragma unroll
                for (int r = 0; r < 4; r++) {
                    int row = gr + r;
                    int bidx = row >> tshift, tt = row & tmask;
                    outq[((((long)(bidx * 16 + h)) << tshift) + tt) * 64 + d] = f2bf(acc[i][j][r] * gamma + bb);
                }
            }
        }
    } else {
        // V^T epilogue: C tile -> LDS [col][tt] (swizzled) -> coalesced b128 stores
        __syncthreads();
        char* Ct = smem;
#pragma unroll
        for (int i = 0; i < 4; i++) {
            int tt = wm + i * 16 + lh * 4;
#pragma unroll
            for (int j = 0; j < 4; j++) {
                int c = wn + j * 16 + lq;
                float bb = bias[n0 + c];
                uint2 pk;
                pk.x = pack2bf(acc[i][j][0] * gamma + bb, acc[i][j][1] * gamma + bb);
                pk.y = pack2bf(acc[i][j][2] * gamma + bb, acc[i][j][3] * gamma + bb);
                int slot = (tt >> 3) ^ (c & 15);
                *(uint2*)(Ct + c * 256 + slot * 16 + (tt & 7) * 2) = pk;
            }
        }
        __syncthreads();
        int b = m0 >> 11, t0 = m0 & 2047;
#pragma unroll
        for (int it = 0; it < 8; it++) {
            int e = it * 256 + tid;
            int c = e >> 4, ch = e & 15;
            int slot = ch ^ (c & 15);
            s8x v = *(const s8x*)(Ct + c * 256 + slot * 16);
            int gcg = n0 + c;
            int h = gcg >> 6, d = gcg & 63;
            *(s8x*)(vtb + ((long)((b * 16 + h) * 64 + d)) * TC_ + t0 + ch * 8) = v;
        }
    }
}

// ---- O GEMM: out = x + attn @ WoT + bo, 128x64 tile (512 blocks = 2/CU) ----
__global__ __launch_bounds__(256) void gemm_o(const u16* __restrict__ A, const u16* __restrict__ Wt,
                                              const float* __restrict__ bias, const float* __restrict__ gsum,
                                              const float* __restrict__ residual, float* __restrict__ outr) {
    __shared__ __align__(16) char smem[24576];   // As 16K | Bs 8K
    int tid = threadIdx.x;
    int w = tid >> 6, l = tid & 63, lq = l & 15, lh = l >> 4;
    int wm = (w >> 1) * 64, wn = (w & 1) * 32;
    int bx = blockIdx.x;
    int m0 = (bx >> 4) * 128, n0 = (bx & 15) * 64;
    char* AsB = smem;
    char* BsB = smem + 16384;
    f4x acc[4][2] = {};
    int rb = tid >> 3;
    int cg = (tid & 7) ^ (rb & 7);
    const u16* Ag = A + (long)m0 * 1024 + cg * 8;
    const u16* Bg = Wt + (long)n0 * 1024 + cg * 8;
    for (int k0 = 0; k0 < 1024; k0 += 64) {
        __syncthreads();
#pragma unroll
        for (int i = 0; i < 4; i++)
            gload16(Ag + (long)(i * 32 + rb) * 1024 + k0, AsB + (i * 256 + tid) * 16);
#pragma unroll
        for (int i = 0; i < 2; i++)
            gload16(Bg + (long)(i * 32 + rb) * 1024 + k0, BsB + (i * 256 + tid) * 16);
        __syncthreads();
#pragma unroll
        for (int s = 0; s < 2; s++) {
            int sl = (s * 4 + lh) ^ (lq & 7);
            s8x af[4], bfr[2];
#pragma unroll
            for (int i = 0; i < 4; i++)
                af[i] = *(const s8x*)(AsB + (wm + i * 16 + lq) * 128 + sl * 16);
#pragma unroll
            for (int j = 0; j < 2; j++)
                bfr[j] = *(const s8x*)(BsB + (wn + j * 16 + lq) * 128 + sl * 16);
#pragma unroll
            for (int i = 0; i < 4; i++)
#pragma unroll
                for (int j = 0; j < 2; j++)
                    acc[i][j] = __builtin_amdgcn_mfma_f32_16x16x32_bf16(af[i], bfr[j], acc[i][j], 0, 0, 0);
        }
    }
    float gamma = gsum[3] * (1.0f / 1048576.0f);
#pragma unroll
    for (int i = 0; i < 4; i++) {
        int gr = m0 + wm + i * 16 + lh * 4;
#pragma unroll
        for (int j = 0; j < 2; j++) {
            int gc = n0 + wn + j * 16 + lq;
            float bb = bias[gc];
#pragma unroll
            for (int r = 0; r < 4; r++) {
                long idx = (long)(gr + r) * 1024 + gc;
                outr[idx] = residual[idx] + acc[i][j][r] * gamma + bb;
            }
        }
    }
}

// ---- flash attention: 128 q/block (32/wave), K-tile 64, single barrier,
//      double-buffered K/V, XOR-swizzled LDS, tile-max, MFMA row-sums --------
__global__ __launch_bounds__(256) void attn_k(const u16* __restrict__ qh, const u16* __restrict__ kh,
                                              const u16* __restrict__ vth, u16* __restrict__ attn) {
    __shared__ __align__(16) char smem[51200];
    int tid = threadIdx.x, w = tid >> 6, l = tid & 63, lq = l & 15, lh = l >> 4;
    int bh = blockIdx.x, q0 = blockIdx.y * 128;
    const u16* qp = qh + ((long)bh * T_ + q0) * 64;
    const u16* kp = kh + (long)bh * TC_ * 64;
    const u16* vp = vth + (long)bh * 64 * TC_;
#pragma unroll
    for (int i = 0; i < 4; i++) {
        int cid = i * 256 + tid;
        int r = cid >> 3, c = (cid & 7) ^ (r & 7);
        gload16(qp + r * 64 + c * 8, smem + cid * 16);
    }
    __syncthreads();
    s8x qf[2][2];   // B-operand: Q[q=w*32+nb*16+lq][d = dh*32 + lh*8 + j]
#pragma unroll
    for (int nb = 0; nb < 2; nb++)
#pragma unroll
        for (int dh = 0; dh < 2; dh++) {
            int qrow = w * 32 + nb * 16 + lq;
            int ch = (dh * 4 + lh) ^ (qrow & 7);
            qf[nb][dh] = *(const s8x*)(smem + qrow * 128 + ch * 16);
        }
    __syncthreads();
#define STAGE_KV(kt, buf)                                                          \
    {                                                                              \
        char* Kb = smem + (buf) * 16384;                                           \
        char* Vb = Kb + 8192;                                                      \
        _Pragma("unroll") for (int i = 0; i < 2; i++) {                            \
            int cid = i * 256 + tid;                                               \
            int r = cid >> 3, c = (cid & 7) ^ (r & 7);                             \
            gload16(kp + ((kt) * 64 + r) * 64 + c * 8, Kb + cid * 16);             \
            gload16(vp + (long)r * TC_ + (kt) * 64 + c * 8, Vb + cid * 16);        \
        }                                                                          \
    }
    STAGE_KV(0, 0);
    f4x oacc[2][4] = {};
    f4x lrun[2] = {};
    float mrun = -1e30f;
    const s8x ones = {16256, 16256, 16256, 16256, 16256, 16256, 16256, 16256};  // bf16 1.0 x8
    char* Psb = smem + 32768 + w * 4608;   // per-wave P: 32 rows x 72 u16
    for (int kt = 0; kt < TC_ / 64; kt++) {
        __syncthreads();
        if (kt + 1 < TC_ / 64) STAGE_KV(kt + 1, (kt + 1) & 1);
        char* Ksb = smem + (kt & 1) * 16384;
        char* Vsb = Ksb + 8192;
        // S^T = K Q^T : rows = k (ni*16 + lh*4 + r), cols = q (nb*16 + lq)
        f4x z[2][4];
#pragma unroll
        for (int ni = 0; ni < 4; ni++) {
            int kr = ni * 16 + lq;
            s8x a0 = *(const s8x*)(Ksb + kr * 128 + ((lh) ^ (kr & 7)) * 16);
            s8x a1 = *(const s8x*)(Ksb + kr * 128 + ((4 + lh) ^ (kr & 7)) * 16);
#pragma unroll
            for (int nb = 0; nb < 2; nb++) {
                f4x zz = {0.f, 0.f, 0.f, 0.f};
                zz = __builtin_amdgcn_mfma_f32_16x16x32_bf16(a0, qf[nb][0], zz, 0, 0, 0);
                zz = __builtin_amdgcn_mfma_f32_16x16x32_bf16(a1, qf[nb][1], zz, 0, 0, 0);
                z[nb][ni] = zz;
            }
        }
        float mx = -1e30f;
#pragma unroll
        for (int nb = 0; nb < 2; nb++)
#pragma unroll
            for (int ni = 0; ni < 4; ni++)
#pragma unroll
                for (int r = 0; r < 4; r++) mx = fmaxf(mx, z[nb][ni][r]);
#pragma unroll
        for (int s = 1; s <= 32; s <<= 1) mx = fmaxf(mx, __shfl_xor(mx, s));
        float mn = fmaxf(mrun, mx);
        float al = __expf(mrun - mn);
        mrun = mn;
        // P = exp(S - m) -> LDS [q][k], packed b64 writes (HW packed bf16 cvt)
#pragma unroll
        for (int nb = 0; nb < 2; nb++) {
            int prow = nb * 16 + lq;
#pragma unroll
            for (int ni = 0; ni < 4; ni++) {
                uint2 pk;
                pk.x = pack2bf(__expf(z[nb][ni][0] - mn), __expf(z[nb][ni][1] - mn));
                pk.y = pack2bf(__expf(z[nb][ni][2] - mn), __expf(z[nb][ni][3] - mn));
                *(uint2*)(Psb + prow * 144 + ni * 32 + lh * 8) = pk;
            }
        }
        if (al != 1.0f) {   // wave-uniform; skip rescale once running max is stable
#pragma unroll
            for (int qb = 0; qb < 2; qb++) {
#pragma unroll
                for (int nd = 0; nd < 4; nd++)
#pragma unroll
                    for (int r = 0; r < 4; r++) oacc[qb][nd][r] *= al;
#pragma unroll
                for (int r = 0; r < 4; r++) lrun[qb][r] *= al;
            }
        }
        s8x vf[4][2];
#pragma unroll
        for (int nd = 0; nd < 4; nd++) {
            int vr = nd * 16 + lq;
            vf[nd][0] = *(const s8x*)(Vsb + vr * 128 + ((lh) ^ (vr & 7)) * 16);
            vf[nd][1] = *(const s8x*)(Vsb + vr * 128 + ((4 + lh) ^ (vr & 7)) * 16);
        }
#pragma unroll
        for (int qb = 0; qb < 2; qb++) {
            int prow = qb * 16 + lq;
            s8x pf0 = *(const s8x*)(Psb + prow * 144 + lh * 16);
            s8x pf1 = *(const s8x*)(Psb + prow * 144 + 64 + lh * 16);
            f4x rs = {0.f, 0.f, 0.f, 0.f};
            rs = __builtin_amdgcn_mfma_f32_16x16x32_bf16(pf0, ones, rs, 0, 0, 0);
            rs = __builtin_amdgcn_mfma_f32_16x16x32_bf16(pf1, ones, rs, 0, 0, 0);
#pragma unroll
            for (int r = 0; r < 4; r++) lrun[qb][r] += rs[r];
#pragma unroll
            for (int nd = 0; nd < 4; nd++) {
                oacc[qb][nd] = __builtin_amdgcn_mfma_f32_16x16x32_bf16(pf0, vf[nd][0], oacc[qb][nd], 0, 0, 0);
                oacc[qb][nd] = __builtin_amdgcn_mfma_f32_16x16x32_bf16(pf1, vf[nd][1], oacc[qb][nd], 0, 0, 0);
            }
        }
    }
    int b = bh >> 4, h = bh & 15;
#pragma unroll
    for (int qb = 0; qb < 2; qb++)
#pragma unroll
        for (int r = 0; r < 4; r++) {
            int q = q0 + w * 32 + qb * 16 + lh * 4 + r;
            float rcp = 1.f / lrun[qb][r];
#pragma unroll
            for (int nd = 0; nd < 4; nd++)
                attn[((long)(b * T_ + q)) * 1024 + h * 64 + nd * 16 + lq] = f2bf(oacc[qb][nd][r] * rcp);
        }
}

extern "C" void kernel_launch(void* const* d_in, const int* in_sizes, int n_in,
                              void* d_out, int out_size, void* d_ws, size_t ws_size,
                              hipStream_t stream) {
    const float* x   = (const float*)d_in[0];
    const float* ctx = (const float*)d_in[1];
    const float* Wq  = (const float*)d_in[2];
    const float* bq  = (const float*)d_in[3];
    const float* Wk  = (const float*)d_in[4];
    const float* bk  = (const float*)d_in[5];
    const float* Wv  = (const float*)d_in[6];
    const float* bv  = (const float*)d_in[7];
    const float* Wo  = (const float*)d_in[8];
    const float* bo  = (const float*)d_in[9];
    const float* lng = (const float*)d_in[10];
    const float* lnb = (const float*)d_in[11];
    float* out = (float*)d_out;

    char* ws = (char*)d_ws;
    float* gsum = (float*)ws;
    size_t off = 256;
    u16* wtq  = (u16*)(ws + off); off += (size_t)1024 * 1024 * 2;
    u16* wtk  = (u16*)(ws + off); off += (size_t)1024 * 1024 * 2;
    u16* wtv  = (u16*)(ws + off); off += (size_t)1024 * 1024 * 2;
    u16* wto  = (u16*)(ws + off); off += (size_t)1024 * 1024 * 2;
    u16* ctxb = (u16*)(ws + off); off += (size_t)8192 * 1024 * 2;
    u16* xn   = (u16*)(ws + off); off += (size_t)4096 * 1024 * 2;   // reused as attn out
    u16* qb_  = (u16*)(ws + off); off += (size_t)4096 * 1024 * 2;
    u16* kb   = (u16*)(ws + off); off += (size_t)8192 * 1024 * 2;
    u16* vtb  = (u16*)(ws + off); off += (size_t)8192 * 1024 * 2;   // ~72MB
    u16* attnb = xn;  // xn dead after gemm_fused

    hipMemsetAsync(gsum, 0, 16, stream);
    absmean_k<<<dim3(128, 4), 256, 0, stream>>>(Wq, Wk, Wv, Wo, gsum);
    prep_k<<<16384, 256, 0, stream>>>(x, lng, lnb, xn, ctx, ctxb,
                                      Wq, Wk, Wv, Wo, wtq, wtk, wtv, wto, gsum);
    gemm_fused<<<1280, 256, 0, stream>>>(xn, ctxb, wtq, wtk, wtv, bq, bk, bv, gsum, qb_, kb, vtb);
    attn_k<<<dim3(64, 8), 256, 0, stream>>>(qb_, kb, vtb, attnb);
    gemm_o<<<512, 256, 0, stream>>>(attnb, wto, bo, gsum, x, out);
}

// Round 5
// 274.862 us; speedup vs baseline: 1.6918x; 1.0252x over previous
//
#include <hip/hip_runtime.h>
#include <hip/hip_bf16.h>

typedef __attribute__((ext_vector_type(8))) short s8x;   // 8 bf16 = 4 VGPRs (MFMA A/B frag)
typedef __attribute__((ext_vector_type(4))) float f4x;   // MFMA C/D frag
typedef unsigned short u16;
typedef unsigned int u32;

#define T_ 1024
#define TC_ 2048
#define SCLOG2E 0.1803368801111243f   // 0.125 * log2(e), folded into q-GEMM for exp2 softmax

__device__ __forceinline__ u16 f2bf(float f) {
    u32 u = __float_as_uint(f);
    return (u16)((u + 0x7fffu + ((u >> 16) & 1u)) >> 16);  // RNE
}

#if defined(__has_builtin)
#if __has_builtin(__builtin_amdgcn_cvt_pk_bf16_f32)
#define HAVE_PK 1
#endif
#endif

// pack two fp32 -> two bf16 (RNE) in one u32; HW packed cvt when available
__device__ __forceinline__ u32 pack2bf(float a, float b) {
#ifdef HAVE_PK
    typedef __attribute__((ext_vector_type(2))) __bf16 bf2t;
    bf2t r = __builtin_amdgcn_cvt_pk_bf16_f32(a, b);
    u32 u;
    __builtin_memcpy(&u, &r, 4);
    return u;
#else
    return (u32)f2bf(a) | ((u32)f2bf(b) << 16);
#endif
}

// async global->LDS, 16B per lane; LDS dst is wave-uniform base + lane*16
__device__ __forceinline__ void gload16(const void* g, void* l) {
    __builtin_amdgcn_global_load_lds((const __attribute__((address_space(1))) u32*)g,
                                     (__attribute__((address_space(3))) u32*)l, 16, 0, 0);
}

// ---- gamma = mean(|W|), 4 weights in one launch ----------------------------
__global__ __launch_bounds__(256) void absmean_k(const float* __restrict__ W0, const float* __restrict__ W1,
                                                 const float* __restrict__ W2, const float* __restrict__ W3,
                                                 float* __restrict__ gsum) {
    int wi = blockIdx.y;
    const float* W = (wi == 0) ? W0 : (wi == 1) ? W1 : (wi == 2) ? W2 : W3;
    const int n4 = (1024 * 1024) / 4;
    float s = 0.f;
    int stride = gridDim.x * blockDim.x;
    for (int i = blockIdx.x * blockDim.x + threadIdx.x; i < n4; i += stride) {
        float4 v = ((const float4*)W)[i];
        s += fabsf(v.x) + fabsf(v.y) + fabsf(v.z) + fabsf(v.w);
    }
#pragma unroll
    for (int off = 32; off; off >>= 1) s += __shfl_down(s, off, 64);
    __shared__ float ps[4];
    if ((threadIdx.x & 63) == 0) ps[threadIdx.x >> 6] = s;
    __syncthreads();
    if (threadIdx.x == 0) atomicAdd(gsum + wi, ps[0] + ps[1] + ps[2] + ps[3]);
}

// ---- merged prep: LN(x)->xn | ctx->bf16 | ternary quantize (one launch) ----
__global__ __launch_bounds__(256) void prep_k(
        const float* __restrict__ x, const float* __restrict__ lng, const float* __restrict__ lnb,
        u16* __restrict__ xn,
        const float* __restrict__ ctx, u16* __restrict__ ctxb,
        const float* __restrict__ W0, const float* __restrict__ W1,
        const float* __restrict__ W2, const float* __restrict__ W3,
        u16* __restrict__ D0, u16* __restrict__ D1, u16* __restrict__ D2, u16* __restrict__ D3,
        const float* __restrict__ gsum) {
    __shared__ float ps[8];
    int bx = blockIdx.x, t = threadIdx.x;
    if (bx < 4096) {                      // LayerNorm row bx
        int row = bx;
        float4 xv = ((const float4*)(x + (long)row * 1024))[t];
        float s = xv.x + xv.y + xv.z + xv.w;
        float s2 = xv.x * xv.x + xv.y * xv.y + xv.z * xv.z + xv.w * xv.w;
#pragma unroll
        for (int off = 32; off; off >>= 1) { s += __shfl_down(s, off, 64); s2 += __shfl_down(s2, off, 64); }
        if ((t & 63) == 0) { ps[t >> 6] = s; ps[4 + (t >> 6)] = s2; }
        __syncthreads();
        float S = ps[0] + ps[1] + ps[2] + ps[3];
        float S2 = ps[4] + ps[5] + ps[6] + ps[7];
        float mu = S * (1.f / 1024.f);
        float var = S2 * (1.f / 1024.f) - mu * mu;
        float rstd = rsqrtf(var + 1e-5f);
        float4 gv = ((const float4*)lng)[t];
        float4 bv = ((const float4*)lnb)[t];
        uint2 o;
        o.x = pack2bf((xv.x - mu) * rstd * gv.x + bv.x, (xv.y - mu) * rstd * gv.y + bv.y);
        o.y = pack2bf((xv.z - mu) * rstd * gv.z + bv.z, (xv.w - mu) * rstd * gv.w + bv.w);
        ((uint2*)(xn + (long)row * 1024))[t] = o;
    } else if (bx < 12288) {              // cast context
        int i = (bx - 4096) * 256 + t;
        float4 v = ((const float4*)ctx)[i];
        uint2 o = {pack2bf(v.x, v.y), pack2bf(v.z, v.w)};
        ((uint2*)ctxb)[i] = o;
    } else {                              // ternary quantize
        int wi = (bx - 12288) >> 10;
        const float* W = (wi == 0) ? W0 : (wi == 1) ? W1 : (wi == 2) ? W2 : W3;
        u16* D = (wi == 0) ? D0 : (wi == 1) ? D1 : (wi == 2) ? D2 : D3;
        float inv = 1.0f / (gsum[wi] * (1.0f / 1048576.0f) + 1e-5f);
        int i = ((bx - 12288) & 1023) * 256 + t;
        float4 wv = ((const float4*)W)[i];
        uint2 o;
        o.x = pack2bf(fminf(1.f, fmaxf(-1.f, rintf(wv.x * inv))),
                      fminf(1.f, fmaxf(-1.f, rintf(wv.y * inv))));
        o.y = pack2bf(fminf(1.f, fmaxf(-1.f, rintf(wv.z * inv))),
                      fminf(1.f, fmaxf(-1.f, rintf(wv.w * inv))));
        ((uint2*)D)[i] = o;
    }
}

// ---- uber GEMM: q (256 blk) | k (512 blk) | v^T (512 blk), BK=64, swizzled LDS
__global__ __launch_bounds__(256) void gemm_fused(
        const u16* __restrict__ xn, const u16* __restrict__ ctxb,
        const u16* __restrict__ wtq, const u16* __restrict__ wtk, const u16* __restrict__ wtv,
        const float* __restrict__ bq, const float* __restrict__ bk, const float* __restrict__ bv,
        const float* __restrict__ gsum,
        u16* __restrict__ qb, u16* __restrict__ kb, u16* __restrict__ vtb) {
    __shared__ __align__(16) char smem[32768];   // As 16K | Bs 16K; reused as 32K C^T tile (prob2)
    int tid = threadIdx.x;
    int w = tid >> 6, l = tid & 63, lq = l & 15, lh = l >> 4;
    int wm = (w >> 1) * 64, wn = (w & 1) * 64;
    int bx = blockIdx.x;
    int prob; const u16 *A, *Wt; const float* bias; int tshift; float sc; int gidx;
    if (bx < 256)      { prob = 0;            A = xn;   Wt = wtq; bias = bq; tshift = 10; sc = SCLOG2E; gidx = 0; }
    else if (bx < 768) { prob = 1; bx -= 256; A = ctxb; Wt = wtk; bias = bk; tshift = 11; sc = 1.0f;  gidx = 1; }
    else               { prob = 2; bx -= 768; A = ctxb; Wt = wtv; bias = bv; tshift = 11; sc = 1.0f;  gidx = 2; }
    int m0 = (bx >> 3) * 128, n0 = (bx & 7) * 128;
    char* AsB = smem;
    char* BsB = smem + 16384;
    f4x acc[4][4] = {};
    int rb = tid >> 3;
    int cg = (tid & 7) ^ (rb & 7);
    const u16* Ag = A + (long)m0 * 1024 + cg * 8;
    const u16* Bg = Wt + (long)n0 * 1024 + cg * 8;
    for (int k0 = 0; k0 < 1024; k0 += 64) {
        __syncthreads();
#pragma unroll
        for (int i = 0; i < 4; i++) {
            gload16(Ag + (long)(i * 32 + rb) * 1024 + k0, AsB + (i * 256 + tid) * 16);
            gload16(Bg + (long)(i * 32 + rb) * 1024 + k0, BsB + (i * 256 + tid) * 16);
        }
        __syncthreads();
#pragma unroll
        for (int s = 0; s < 2; s++) {
            int sl = (s * 4 + lh) ^ (lq & 7);
            s8x af[4], bfr[4];
#pragma unroll
            for (int i = 0; i < 4; i++) {
                af[i] = *(const s8x*)(AsB + (wm + i * 16 + lq) * 128 + sl * 16);
                bfr[i] = *(const s8x*)(BsB + (wn + i * 16 + lq) * 128 + sl * 16);
            }
#pragma unroll
            for (int i = 0; i < 4; i++)
#pragma unroll
                for (int j = 0; j < 4; j++)
                    acc[i][j] = __builtin_amdgcn_mfma_f32_16x16x32_bf16(af[i], bfr[j], acc[i][j], 0, 0, 0);
        }
    }
    float gamma = gsum[gidx] * (1.0f / 1048576.0f) * sc;
    if (prob < 2) {
        u16* outq = (prob == 0) ? qb : kb;
        int tmask = (1 << tshift) - 1;
#pragma unroll
        for (int i = 0; i < 4; i++) {
            int gr = m0 + wm + i * 16 + lh * 4;
#pragma unroll
            for (int j = 0; j < 4; j++) {
                int gc = n0 + wn + j * 16 + lq;
                float bb = bias[gc] * sc;
                int h = gc >> 6, d = gc & 63;
#pragma unroll
                for (int r = 0; r < 4; r++) {
                    int row = gr + r;
                    int bidx = row >> tshift, tt = row & tmask;
                    outq[((((long)(bidx * 16 + h)) << tshift) + tt) * 64 + d] = f2bf(acc[i][j][r] * gamma + bb);
                }
            }
        }
    } else {
        // V^T epilogue: C tile -> LDS [col][tt] (swizzled) -> coalesced b128 stores
        __syncthreads();
        char* Ct = smem;
#pragma unroll
        for (int i = 0; i < 4; i++) {
            int tt = wm + i * 16 + lh * 4;
#pragma unroll
            for (int j = 0; j < 4; j++) {
                int c = wn + j * 16 + lq;
                float bb = bias[n0 + c];
                uint2 pk;
                pk.x = pack2bf(acc[i][j][0] * gamma + bb, acc[i][j][1] * gamma + bb);
                pk.y = pack2bf(acc[i][j][2] * gamma + bb, acc[i][j][3] * gamma + bb);
                int slot = (tt >> 3) ^ (c & 15);
                *(uint2*)(Ct + c * 256 + slot * 16 + (tt & 7) * 2) = pk;
            }
        }
        __syncthreads();
        int b = m0 >> 11, t0 = m0 & 2047;
#pragma unroll
        for (int it = 0; it < 8; it++) {
            int e = it * 256 + tid;
            int c = e >> 4, ch = e & 15;
            int slot = ch ^ (c & 15);
            s8x v = *(const s8x*)(Ct + c * 256 + slot * 16);
            int gcg = n0 + c;
            int h = gcg >> 6, d = gcg & 63;
            *(s8x*)(vtb + ((long)((b * 16 + h) * 64 + d)) * TC_ + t0 + ch * 8) = v;
        }
    }
}

// ---- O GEMM: out = x + attn @ WoT + bo, 128x64 tile (512 blocks = 2/CU) ----
__global__ __launch_bounds__(256) void gemm_o(const u16* __restrict__ A, const u16* __restrict__ Wt,
                                              const float* __restrict__ bias, const float* __restrict__ gsum,
                                              const float* __restrict__ residual, float* __restrict__ outr) {
    __shared__ __align__(16) char smem[24576];   // As 16K | Bs 8K
    int tid = threadIdx.x;
    int w = tid >> 6, l = tid & 63, lq = l & 15, lh = l >> 4;
    int wm = (w >> 1) * 64, wn = (w & 1) * 32;
    int bx = blockIdx.x;
    int m0 = (bx >> 4) * 128, n0 = (bx & 15) * 64;
    char* AsB = smem;
    char* BsB = smem + 16384;
    f4x acc[4][2] = {};
    int rb = tid >> 3;
    int cg = (tid & 7) ^ (rb & 7);
    const u16* Ag = A + (long)m0 * 1024 + cg * 8;
    const u16* Bg = Wt + (long)n0 * 1024 + cg * 8;
    for (int k0 = 0; k0 < 1024; k0 += 64) {
        __syncthreads();
#pragma unroll
        for (int i = 0; i < 4; i++)
            gload16(Ag + (long)(i * 32 + rb) * 1024 + k0, AsB + (i * 256 + tid) * 16);
#pragma unroll
        for (int i = 0; i < 2; i++)
            gload16(Bg + (long)(i * 32 + rb) * 1024 + k0, BsB + (i * 256 + tid) * 16);
        __syncthreads();
#pragma unroll
        for (int s = 0; s < 2; s++) {
            int sl = (s * 4 + lh) ^ (lq & 7);
            s8x af[4], bfr[2];
#pragma unroll
            for (int i = 0; i < 4; i++)
                af[i] = *(const s8x*)(AsB + (wm + i * 16 + lq) * 128 + sl * 16);
#pragma unroll
            for (int j = 0; j < 2; j++)
                bfr[j] = *(const s8x*)(BsB + (wn + j * 16 + lq) * 128 + sl * 16);
#pragma unroll
            for (int i = 0; i < 4; i++)
#pragma unroll
                for (int j = 0; j < 2; j++)
                    acc[i][j] = __builtin_amdgcn_mfma_f32_16x16x32_bf16(af[i], bfr[j], acc[i][j], 0, 0, 0);
        }
    }
    float gamma = gsum[3] * (1.0f / 1048576.0f);
#pragma unroll
    for (int i = 0; i < 4; i++) {
        int gr = m0 + wm + i * 16 + lh * 4;
#pragma unroll
        for (int j = 0; j < 2; j++) {
            int gc = n0 + wn + j * 16 + lq;
            float bb = bias[gc];
#pragma unroll
            for (int r = 0; r < 4; r++) {
                long idx = (long)(gr + r) * 1024 + gc;
                outr[idx] = residual[idx] + acc[i][j][r] * gamma + bb;
            }
        }
    }
}

// ---- flash attention v3: 512 threads (8 waves), 128 q/block, 16 q/wave,
//      K-tile 64, dbuf K/V, XOR-swizzled LDS, tile-max, exp2, MFMA row-sums --
// q comes pre-scaled by 0.125*log2e -> softmax via exp2 (exact base change).
__global__ __launch_bounds__(512) void attn_k(const u16* __restrict__ qh, const u16* __restrict__ kh,
                                              const u16* __restrict__ vth, u16* __restrict__ attn) {
    // LDS: [0,16K) KV buf0 (Ks 8K | Vs 8K), [16K,32K) KV buf1, [32K,50K) P (8 waves x 16 x 72 u16)
    __shared__ __align__(16) char smem[51200];
    int tid = threadIdx.x, w = tid >> 6, l = tid & 63, lq = l & 15, lh = l >> 4;
    int bh = blockIdx.x, q0 = blockIdx.y * 128;
    const u16* qp = qh + ((long)bh * T_ + q0) * 64;
    const u16* kp = kh + (long)bh * TC_ * 64;
    const u16* vp = vth + (long)bh * 64 * TC_;
    // stage Q 128x64 (swizzled), transient in KV buf0 region
#pragma unroll
    for (int i = 0; i < 2; i++) {
        int cid = i * 512 + tid;
        int r = cid >> 3, c = (cid & 7) ^ (r & 7);
        gload16(qp + r * 64 + c * 8, smem + cid * 16);
    }
    __syncthreads();
    s8x qf0, qf1;   // B-operand: Q[q = w*16+lq][d = dh*32 + lh*8 + j]
    {
        int qrow = w * 16 + lq;
        qf0 = *(const s8x*)(smem + qrow * 128 + ((lh) ^ (qrow & 7)) * 16);
        qf1 = *(const s8x*)(smem + qrow * 128 + ((4 + lh) ^ (qrow & 7)) * 16);
    }
    __syncthreads();   // Q region about to be overwritten by KV buf0
#define STAGE_KV(kt, buf)                                                      \
    {                                                                          \
        char* Kb = smem + (buf) * 16384;                                       \
        char* Vb = Kb + 8192;                                                  \
        int r = tid >> 3, c = (tid & 7) ^ (r & 7);                             \
        gload16(kp + ((kt) * 64 + r) * 64 + c * 8, Kb + tid * 16);             \
        gload16(vp + (long)r * TC_ + (kt) * 64 + c * 8, Vb + tid * 16);        \
    }
    STAGE_KV(0, 0);
    f4x oacc[4] = {};
    f4x lrun = {};
    float mrun = -1e30f;
    const s8x ones = {16256, 16256, 16256, 16256, 16256, 16256, 16256, 16256};  // bf16 1.0 x8
    char* Psb = smem + 32768 + w * 2304;   // per-wave P: 16 rows x 72 u16 (pad -> conflict-free)
    for (int kt = 0; kt < TC_ / 64; kt++) {
        __syncthreads();                     // drains vmcnt -> tile kt visible; protects buf reuse
        if (kt + 1 < TC_ / 64) STAGE_KV(kt + 1, (kt + 1) & 1);
        char* Ksb = smem + (kt & 1) * 16384;
        char* Vsb = Ksb + 8192;
        // S^T = K Q^T : rows = k (ni*16 + lh*4 + r), cols = q (w*16 + lq)
        f4x z[4];
#pragma unroll
        for (int ni = 0; ni < 4; ni++) {
            int kr = ni * 16 + lq;
            s8x a0 = *(const s8x*)(Ksb + kr * 128 + ((lh) ^ (kr & 7)) * 16);
            s8x a1 = *(const s8x*)(Ksb + kr * 128 + ((4 + lh) ^ (kr & 7)) * 16);
            f4x zz = {0.f, 0.f, 0.f, 0.f};
            zz = __builtin_amdgcn_mfma_f32_16x16x32_bf16(a0, qf0, zz, 0, 0, 0);
            zz = __builtin_amdgcn_mfma_f32_16x16x32_bf16(a1, qf1, zz, 0, 0, 0);
            z[ni] = zz;
        }
        // tile-wide max (upper bound per q-row -> exact online softmax)
        float mx = fmaxf(fmaxf(fmaxf(z[0][0], z[0][1]), fmaxf(z[0][2], z[0][3])),
                         fmaxf(fmaxf(z[1][0], z[1][1]), fmaxf(z[1][2], z[1][3])));
        mx = fmaxf(mx, fmaxf(fmaxf(fmaxf(z[2][0], z[2][1]), fmaxf(z[2][2], z[2][3])),
                             fmaxf(fmaxf(z[3][0], z[3][1]), fmaxf(z[3][2], z[3][3]))));
#pragma unroll
        for (int s = 1; s <= 32; s <<= 1) mx = fmaxf(mx, __shfl_xor(mx, s));
        float mn = fmaxf(mrun, mx);
        float al = __builtin_amdgcn_exp2f(mrun - mn);
        mrun = mn;
        // P = exp2(z - m) -> LDS [q][k], packed b64 writes
#pragma unroll
        for (int ni = 0; ni < 4; ni++) {
            uint2 pk;
            pk.x = pack2bf(__builtin_amdgcn_exp2f(z[ni][0] - mn), __builtin_amdgcn_exp2f(z[ni][1] - mn));
            pk.y = pack2bf(__builtin_amdgcn_exp2f(z[ni][2] - mn), __builtin_amdgcn_exp2f(z[ni][3] - mn));
            *(uint2*)(Psb + lq * 144 + ni * 32 + lh * 8) = pk;
        }
        if (al != 1.0f) {   // wave-uniform; skip once running max is stable
#pragma unroll
            for (int nd = 0; nd < 4; nd++)
#pragma unroll
                for (int r = 0; r < 4; r++) oacc[nd][r] *= al;
#pragma unroll
            for (int r = 0; r < 4; r++) lrun[r] *= al;
        }
        s8x vf0[4], vf1[4];
#pragma unroll
        for (int nd = 0; nd < 4; nd++) {
            int vr = nd * 16 + lq;
            vf0[nd] = *(const s8x*)(Vsb + vr * 128 + ((lh) ^ (vr & 7)) * 16);
            vf1[nd] = *(const s8x*)(Vsb + vr * 128 + ((4 + lh) ^ (vr & 7)) * 16);
        }
        s8x pf0 = *(const s8x*)(Psb + lq * 144 + lh * 16);
        s8x pf1 = *(const s8x*)(Psb + lq * 144 + 64 + lh * 16);
        f4x rs = {0.f, 0.f, 0.f, 0.f};
        rs = __builtin_amdgcn_mfma_f32_16x16x32_bf16(pf0, ones, rs, 0, 0, 0);
        rs = __builtin_amdgcn_mfma_f32_16x16x32_bf16(pf1, ones, rs, 0, 0, 0);
#pragma unroll
        for (int r = 0; r < 4; r++) lrun[r] += rs[r];
#pragma unroll
        for (int nd = 0; nd < 4; nd++) {
            oacc[nd] = __builtin_amdgcn_mfma_f32_16x16x32_bf16(pf0, vf0[nd], oacc[nd], 0, 0, 0);
            oacc[nd] = __builtin_amdgcn_mfma_f32_16x16x32_bf16(pf1, vf1[nd], oacc[nd], 0, 0, 0);
        }
    }
    int b = bh >> 4, h = bh & 15;
#pragma unroll
    for (int r = 0; r < 4; r++) {
        int q = q0 + w * 16 + lh * 4 + r;
        float rcp = 1.f / lrun[r];
#pragma unroll
        for (int nd = 0; nd < 4; nd++)
            attn[((long)(b * T_ + q)) * 1024 + h * 64 + nd * 16 + lq] = f2bf(oacc[nd][r] * rcp);
    }
}

extern "C" void kernel_launch(void* const* d_in, const int* in_sizes, int n_in,
                              void* d_out, int out_size, void* d_ws, size_t ws_size,
                              hipStream_t stream) {
    const float* x   = (const float*)d_in[0];
    const float* ctx = (const float*)d_in[1];
    const float* Wq  = (const float*)d_in[2];
    const float* bq  = (const float*)d_in[3];
    const float* Wk  = (const float*)d_in[4];
    const float* bk  = (const float*)d_in[5];
    const float* Wv  = (const float*)d_in[6];
    const float* bv  = (const float*)d_in[7];
    const float* Wo  = (const float*)d_in[8];
    const float* bo  = (const float*)d_in[9];
    const float* lng = (const float*)d_in[10];
    const float* lnb = (const float*)d_in[11];
    float* out = (float*)d_out;

    char* ws = (char*)d_ws;
    float* gsum = (float*)ws;
    size_t off = 256;
    u16* wtq  = (u16*)(ws + off); off += (size_t)1024 * 1024 * 2;
    u16* wtk  = (u16*)(ws + off); off += (size_t)1024 * 1024 * 2;
    u16* wtv  = (u16*)(ws + off); off += (size_t)1024 * 1024 * 2;
    u16* wto  = (u16*)(ws + off); off += (size_t)1024 * 1024 * 2;
    u16* ctxb = (u16*)(ws + off); off += (size_t)8192 * 1024 * 2;
    u16* xn   = (u16*)(ws + off); off += (size_t)4096 * 1024 * 2;   // reused as attn out
    u16* qb_  = (u16*)(ws + off); off += (size_t)4096 * 1024 * 2;
    u16* kb   = (u16*)(ws + off); off += (size_t)8192 * 1024 * 2;
    u16* vtb  = (u16*)(ws + off); off += (size_t)8192 * 1024 * 2;   // ~72MB
    u16* attnb = xn;  // xn dead after gemm_fused

    hipMemsetAsync(gsum, 0, 16, stream);
    absmean_k<<<dim3(128, 4), 256, 0, stream>>>(Wq, Wk, Wv, Wo, gsum);
    prep_k<<<16384, 256, 0, stream>>>(x, lng, lnb, xn, ctx, ctxb,
                                      Wq, Wk, Wv, Wo, wtq, wtk, wtv, wto, gsum);
    gemm_fused<<<1280, 256, 0, stream>>>(xn, ctxb, wtq, wtk, wtv, bq, bk, bv, gsum, qb_, kb, vtb);
    attn_k<<<dim3(64, 8), 512, 0, stream>>>(qb_, kb, vtb, attnb);
    gemm_o<<<512, 256, 0, stream>>>(attnb, wto, bo, gsum, x, out);
}